// Round 1
// baseline (1016.221 us; speedup 1.0000x reference)
//
#include <hip/hip_runtime.h>
#include <hip/hip_bf16.h>

#define N_NODES 50000
#define N_EDGES 500000
#define D_IN    128
#define D_K     384
#define D_OUT   128
#define BN_EPS  1e-5f

typedef __bf16 bf16x8 __attribute__((ext_vector_type(8)));
typedef float  f32x4  __attribute__((ext_vector_type(4)));

// ---- workspace layout (bytes) ----
// recv:  [0, 25.6MB)              f32 [50000][128]
// send:  [25.6MB, 51.2MB)         f32 [50000][128]
// Wbf16: [51.2MB, +98304)         bf16 [128][384]
// stats: sum/sumsq/scale/shift    512B each
#define OFF_RECV  0ULL
#define OFF_SEND  25600000ULL
#define OFF_WBF   51200000ULL
#define OFF_SUM   51298304ULL
#define OFF_SUMSQ 51298816ULL
#define OFF_SCALE 51299328ULL
#define OFF_SHIFT 51299840ULL

// ---------------- W f32 -> bf16 ----------------
__global__ void wcvt_kernel(const float* __restrict__ W, __bf16* __restrict__ Wb) {
    int i = blockIdx.x * blockDim.x + threadIdx.x;
    if (i < D_OUT * D_K) Wb[i] = (__bf16)W[i];
}

// ---------------- scatter-add edges -> recv/send ----------------
__global__ __launch_bounds__(256) void scatter_kernel(
    const float* __restrict__ edge_attr, const int* __restrict__ row,
    const int* __restrict__ col, float* __restrict__ recv, float* __restrict__ send) {
    const int lane = threadIdx.x & 63;
    const int wid  = blockIdx.x * (blockDim.x >> 6) + (threadIdx.x >> 6);
    const int nw   = gridDim.x * (blockDim.x >> 6);
    for (int e0 = wid; e0 < N_EDGES; e0 += nw) {
        const int e = __builtin_amdgcn_readfirstlane(e0);   // scalarize index loads
        const int c = col[e];
        const int r = row[e];
        const float2 v = ((const float2*)(edge_attr + (size_t)e * D_IN))[lane];
        float* pr = recv + (size_t)c * D_IN + 2 * lane;
        float* ps = send + (size_t)r * D_IN + 2 * lane;
        unsafeAtomicAdd(pr,     v.x);
        unsafeAtomicAdd(pr + 1, v.y);
        unsafeAtomicAdd(ps,     v.x);
        unsafeAtomicAdd(ps + 1, v.y);
    }
}

// ---------------- fused GEMM (bf16 MFMA) + bias + ReLU + BN-stats ----------------
// block = 256 threads (4 waves); block tile = 64 nodes x 128 ch;
// wave w -> nodes [blk*64 + w*16, +16), all 128 channels (8 col-frags).
__global__ __launch_bounds__(256) void gemm_kernel(
    const float* __restrict__ recv, const float* __restrict__ send,
    const float* __restrict__ node_attr, const __bf16* __restrict__ Wb,
    const float* __restrict__ bias, float* __restrict__ h,
    float* __restrict__ sum, float* __restrict__ sumsq) {
    const int lane = threadIdx.x & 63;
    const int w    = threadIdx.x >> 6;
    const int m    = lane & 15;   // A-row (node) / C-col (channel) lane index
    const int g    = lane >> 4;   // k-group
    const int nodeA  = blockIdx.x * 64 + w * 16 + m;
    const bool validA = nodeA < N_NODES;

    f32x4 acc[8];
#pragma unroll
    for (int f = 0; f < 8; ++f) acc[f] = (f32x4)0.0f;

    const float* seg[3] = {recv, send, node_attr};
#pragma unroll
    for (int ks = 0; ks < 12; ++ks) {
        const int k0 = ks * 32;
        const float* base = seg[k0 >> 7] + (size_t)nodeA * D_IN + (k0 & 127) + g * 8;
        f32x4 v0 = (f32x4)0.0f, v1 = (f32x4)0.0f;
        if (validA) {
            v0 = *(const f32x4*)(base);
            v1 = *(const f32x4*)(base + 4);
        }
        bf16x8 a;
#pragma unroll
        for (int i = 0; i < 4; ++i) { a[i] = (__bf16)v0[i]; a[i + 4] = (__bf16)v1[i]; }
#pragma unroll
        for (int f = 0; f < 8; ++f) {
            const __bf16* wp = Wb + (size_t)(f * 16 + m) * D_K + k0 + g * 8;
            bf16x8 bfrag = *(const bf16x8*)wp;
            acc[f] = __builtin_amdgcn_mfma_f32_16x16x32_bf16(a, bfrag, acc[f], 0, 0, 0);
        }
    }

    // epilogue: bias + relu + write h (f32, into d_out) + per-channel stats
#pragma unroll
    for (int f = 0; f < 8; ++f) {
        const int j  = f * 16 + m;            // channel  (C col = lane&15)
        const float bj = bias[j];
        float s1 = 0.0f, s2 = 0.0f;
#pragma unroll
        for (int r = 0; r < 4; ++r) {
            const int nodeC = blockIdx.x * 64 + w * 16 + g * 4 + r;   // C row
            float v = acc[f][r] + bj;
            v = v > 0.0f ? v : 0.0f;
            if (nodeC < N_NODES) {
                h[(size_t)nodeC * D_OUT + j] = v;
                s1 += v;
                s2 += v * v;
            }
        }
        s1 += __shfl_xor(s1, 16, 64);  s2 += __shfl_xor(s2, 16, 64);
        s1 += __shfl_xor(s1, 32, 64);  s2 += __shfl_xor(s2, 32, 64);
        if (lane < 16) {
            unsafeAtomicAdd(&sum[j], s1);
            unsafeAtomicAdd(&sumsq[j], s2);
        }
    }
}

// ---------------- BN finalize: per-channel scale/shift ----------------
__global__ void bn_finalize_kernel(const float* __restrict__ sum, const float* __restrict__ sumsq,
                                   const float* __restrict__ gamma, const float* __restrict__ beta,
                                   float* __restrict__ scale, float* __restrict__ shift) {
    int j = threadIdx.x;
    if (j < D_OUT) {
        const float inv_n = 1.0f / (float)N_NODES;
        float mu  = sum[j] * inv_n;
        float var = sumsq[j] * inv_n - mu * mu;
        float sc  = gamma[j] * rsqrtf(var + BN_EPS);
        scale[j] = sc;
        shift[j] = beta[j] - mu * sc;
    }
}

// ---------------- BN apply (in-place on d_out) ----------------
__global__ __launch_bounds__(256) void bn_apply_kernel(
    float* __restrict__ h, const float* __restrict__ scale, const float* __restrict__ shift) {
    size_t i = ((size_t)blockIdx.x * blockDim.x + threadIdx.x) * 8;
    if (i >= (size_t)N_NODES * D_OUT) return;
    const int j0 = (int)(i & 127);
    f32x4 a = *(const f32x4*)(h + i);
    f32x4 b = *(const f32x4*)(h + i + 4);
#pragma unroll
    for (int q = 0; q < 4; ++q) {
        a[q] = a[q] * scale[j0 + q]     + shift[j0 + q];
        b[q] = b[q] * scale[j0 + 4 + q] + shift[j0 + 4 + q];
    }
    *(f32x4*)(h + i)     = a;
    *(f32x4*)(h + i + 4) = b;
}

extern "C" void kernel_launch(void* const* d_in, const int* in_sizes, int n_in,
                              void* d_out, int out_size, void* d_ws, size_t ws_size,
                              hipStream_t stream) {
    const float* edge_attr = (const float*)d_in[0];
    const float* node_attr = (const float*)d_in[1];
    const float* W         = (const float*)d_in[2];
    const float* bias      = (const float*)d_in[3];
    const float* gamma     = (const float*)d_in[4];
    const float* beta      = (const float*)d_in[5];
    const int*   row       = (const int*)d_in[6];
    const int*   col       = (const int*)d_in[7];
    float* out = (float*)d_out;

    char* ws = (char*)d_ws;
    float*  recv  = (float*)(ws + OFF_RECV);
    float*  send  = (float*)(ws + OFF_SEND);
    __bf16* Wb    = (__bf16*)(ws + OFF_WBF);
    float*  sum   = (float*)(ws + OFF_SUM);
    float*  sumsq = (float*)(ws + OFF_SUMSQ);
    float*  scale = (float*)(ws + OFF_SCALE);
    float*  shift = (float*)(ws + OFF_SHIFT);

    // zero accumulators (recv+send) and stats
    hipMemsetAsync(ws, 0, OFF_WBF, stream);
    hipMemsetAsync(ws + OFF_SUM, 0, 2048, stream);

    wcvt_kernel<<<(D_OUT * D_K + 255) / 256, 256, 0, stream>>>(W, Wb);
    scatter_kernel<<<2048, 256, 0, stream>>>(edge_attr, row, col, recv, send);
    gemm_kernel<<<(N_NODES + 63) / 64, 256, 0, stream>>>(recv, send, node_attr, Wb,
                                                         bias, out, sum, sumsq);
    bn_finalize_kernel<<<1, 128, 0, stream>>>(sum, sumsq, gamma, beta, scale, shift);
    bn_apply_kernel<<<(N_NODES * D_OUT / 8 + 255) / 256, 256, 0, stream>>>(out, scale, shift);
}

// Round 2
// 694.099 us; speedup vs baseline: 1.4641x; 1.4641x over previous
//
#include <hip/hip_runtime.h>
#include <hip/hip_bf16.h>

#define N_NODES 50000
#define N_EDGES 500000
#define D_IN    128
#define D_K     384
#define D_OUT   128
#define BN_EPS  1e-5f
#define N_TASK  (2 * N_NODES)   // recv tasks then send tasks

typedef __bf16 bf16x8 __attribute__((ext_vector_type(8)));
typedef float  f32x4  __attribute__((ext_vector_type(4)));

// ---- workspace layout (bytes) ----
#define OFF_AGG   0ULL           // bf16 [2][50000][128] = 25,600,000
#define OFF_CNT   25600000ULL    // int  [100000]        =    400,000
#define OFF_OFF   26000000ULL    // int  [100001]        =    400,004 (+pad)
#define OFF_CUR   26400256ULL    // int  [100000]        =    400,000
#define OFF_EID   26800256ULL    // int  [1000000]       =  4,000,000
#define OFF_WBF   30800256ULL    // bf16 [128][384]      =     98,304
#define OFF_SUM   30898560ULL
#define OFF_SUMSQ 30899072ULL
#define OFF_SCALE 30899584ULL
#define OFF_SHIFT 30900096ULL

// ---------------- W f32 -> bf16 ----------------
__global__ void wcvt_kernel(const float* __restrict__ W, __bf16* __restrict__ Wb) {
    int i = blockIdx.x * blockDim.x + threadIdx.x;
    if (i < D_OUT * D_K) Wb[i] = (__bf16)W[i];
}

// ---------------- degree histogram ----------------
__global__ __launch_bounds__(256) void hist_kernel(const int* __restrict__ row,
                                                   const int* __restrict__ col,
                                                   int* __restrict__ cnt) {
    int i = blockIdx.x * blockDim.x + threadIdx.x;
    if (i < N_EDGES) {
        atomicAdd(&cnt[col[i]], 1);
        atomicAdd(&cnt[N_NODES + row[i]], 1);
    }
}

// ---------------- single-block exclusive scan over 100000 counts ----------------
__global__ __launch_bounds__(1024) void scan_kernel(const int* __restrict__ cnt,
                                                    int* __restrict__ off,
                                                    int* __restrict__ cur) {
    __shared__ int s[1024];
    const int t = threadIdx.x;
    const int CH = (N_TASK + 1023) / 1024;   // 98
    const int base = t * CH;
    int local = 0;
    for (int i = 0; i < CH; ++i) {
        int idx = base + i;
        if (idx < N_TASK) local += cnt[idx];
    }
    s[t] = local;
    __syncthreads();
    for (int ofs = 1; ofs < 1024; ofs <<= 1) {
        int v = (t >= ofs) ? s[t - ofs] : 0;
        __syncthreads();
        s[t] += v;
        __syncthreads();
    }
    int run = (t == 0) ? 0 : s[t - 1];
    for (int i = 0; i < CH; ++i) {
        int idx = base + i;
        if (idx < N_TASK) {
            off[idx] = run;
            cur[idx] = run;
            run += cnt[idx];
        }
    }
    if (t == 1023) off[N_TASK] = s[1023];
}

// ---------------- scatter edge ids into CSR ----------------
__global__ __launch_bounds__(256) void sid_kernel(const int* __restrict__ row,
                                                  const int* __restrict__ col,
                                                  int* __restrict__ cur,
                                                  int* __restrict__ eid) {
    int i = blockIdx.x * blockDim.x + threadIdx.x;
    if (i < N_EDGES) {
        int p = atomicAdd(&cur[col[i]], 1);
        eid[p] = i;
        int q = atomicAdd(&cur[N_NODES + row[i]], 1);
        eid[q] = i;
    }
}

// ---------------- gather-sum: one wave per (node, side) task ----------------
__global__ __launch_bounds__(256) void gather_kernel(const float* __restrict__ edge_attr,
                                                     const int* __restrict__ off,
                                                     const int* __restrict__ eid,
                                                     __bf16* __restrict__ agg) {
    const int lane = threadIdx.x & 63;
    const int wid  = blockIdx.x * 4 + (threadIdx.x >> 6);
    if (wid >= N_TASK) return;
    const int beg = off[wid];
    const int end = off[wid + 1];
    float2 acc = {0.0f, 0.0f};
    for (int i = beg; i < end; ++i) {
        const int e = eid[i];
        const float2 v = ((const float2*)(edge_attr + (size_t)e * D_IN))[lane];
        acc.x += v.x;
        acc.y += v.y;
    }
    __bf16* p = agg + (size_t)wid * D_IN + 2 * lane;
    p[0] = (__bf16)acc.x;
    p[1] = (__bf16)acc.y;
}

// ---------------- fused GEMM (bf16 MFMA) + bias + ReLU + BN-stats ----------------
__global__ __launch_bounds__(256) void gemm_kernel(
    const __bf16* __restrict__ agg, const float* __restrict__ node_attr,
    const __bf16* __restrict__ Wb, const float* __restrict__ bias,
    float* __restrict__ h, float* __restrict__ sum, float* __restrict__ sumsq) {
    const int lane = threadIdx.x & 63;
    const int w    = threadIdx.x >> 6;
    const int m    = lane & 15;   // A-row (node) / C-col (channel) lane index
    const int g    = lane >> 4;   // k-group
    const int nodeA  = blockIdx.x * 64 + w * 16 + m;
    const bool validA = nodeA < N_NODES;

    f32x4 acc[8];
#pragma unroll
    for (int f = 0; f < 8; ++f) acc[f] = (f32x4)0.0f;

#pragma unroll
    for (int ks = 0; ks < 12; ++ks) {
        const int k0 = ks * 32;
        bf16x8 a;
#pragma unroll
        for (int i = 0; i < 8; ++i) a[i] = (__bf16)0.0f;
        if (validA) {
            if (ks < 8) {   // recv (seg 0) / send (seg 1) stored bf16
                const __bf16* p = agg + (size_t)(k0 >> 7) * (N_NODES * D_IN)
                                      + (size_t)nodeA * D_IN + (k0 & 127) + g * 8;
                a = *(const bf16x8*)p;
            } else {        // node_attr f32 -> bf16
                const float* p = node_attr + (size_t)nodeA * D_IN + (k0 - 256) + g * 8;
                f32x4 v0 = *(const f32x4*)p;
                f32x4 v1 = *(const f32x4*)(p + 4);
#pragma unroll
                for (int i = 0; i < 4; ++i) { a[i] = (__bf16)v0[i]; a[i + 4] = (__bf16)v1[i]; }
            }
        }
#pragma unroll
        for (int f = 0; f < 8; ++f) {
            const __bf16* wp = Wb + (size_t)(f * 16 + m) * D_K + k0 + g * 8;
            bf16x8 bfrag = *(const bf16x8*)wp;
            acc[f] = __builtin_amdgcn_mfma_f32_16x16x32_bf16(a, bfrag, acc[f], 0, 0, 0);
        }
    }

    // epilogue: bias + relu + write h (f32, into d_out) + per-channel stats
#pragma unroll
    for (int f = 0; f < 8; ++f) {
        const int j  = f * 16 + m;            // channel (C col = lane&15)
        const float bj = bias[j];
        float s1 = 0.0f, s2 = 0.0f;
#pragma unroll
        for (int r = 0; r < 4; ++r) {
            const int nodeC = blockIdx.x * 64 + w * 16 + g * 4 + r;   // C row
            float v = acc[f][r] + bj;
            v = v > 0.0f ? v : 0.0f;
            if (nodeC < N_NODES) {
                h[(size_t)nodeC * D_OUT + j] = v;
                s1 += v;
                s2 += v * v;
            }
        }
        s1 += __shfl_xor(s1, 16, 64);  s2 += __shfl_xor(s2, 16, 64);
        s1 += __shfl_xor(s1, 32, 64);  s2 += __shfl_xor(s2, 32, 64);
        if (lane < 16) {
            unsafeAtomicAdd(&sum[j], s1);
            unsafeAtomicAdd(&sumsq[j], s2);
        }
    }
}

// ---------------- BN finalize ----------------
__global__ void bn_finalize_kernel(const float* __restrict__ sum, const float* __restrict__ sumsq,
                                   const float* __restrict__ gamma, const float* __restrict__ beta,
                                   float* __restrict__ scale, float* __restrict__ shift) {
    int j = threadIdx.x;
    if (j < D_OUT) {
        const float inv_n = 1.0f / (float)N_NODES;
        float mu  = sum[j] * inv_n;
        float var = sumsq[j] * inv_n - mu * mu;
        float sc  = gamma[j] * rsqrtf(var + BN_EPS);
        scale[j] = sc;
        shift[j] = beta[j] - mu * sc;
    }
}

// ---------------- BN apply (in-place on d_out) ----------------
__global__ __launch_bounds__(256) void bn_apply_kernel(
    float* __restrict__ h, const float* __restrict__ scale, const float* __restrict__ shift) {
    size_t i = ((size_t)blockIdx.x * blockDim.x + threadIdx.x) * 8;
    if (i >= (size_t)N_NODES * D_OUT) return;
    const int j0 = (int)(i & 127);
    f32x4 a = *(const f32x4*)(h + i);
    f32x4 b = *(const f32x4*)(h + i + 4);
#pragma unroll
    for (int q = 0; q < 4; ++q) {
        a[q] = a[q] * scale[j0 + q]     + shift[j0 + q];
        b[q] = b[q] * scale[j0 + 4 + q] + shift[j0 + 4 + q];
    }
    *(f32x4*)(h + i)     = a;
    *(f32x4*)(h + i + 4) = b;
}

extern "C" void kernel_launch(void* const* d_in, const int* in_sizes, int n_in,
                              void* d_out, int out_size, void* d_ws, size_t ws_size,
                              hipStream_t stream) {
    const float* edge_attr = (const float*)d_in[0];
    const float* node_attr = (const float*)d_in[1];
    const float* W         = (const float*)d_in[2];
    const float* bias      = (const float*)d_in[3];
    const float* gamma     = (const float*)d_in[4];
    const float* beta      = (const float*)d_in[5];
    const int*   row       = (const int*)d_in[6];
    const int*   col       = (const int*)d_in[7];
    float* out = (float*)d_out;

    char* ws = (char*)d_ws;
    __bf16* agg   = (__bf16*)(ws + OFF_AGG);
    int*    cnt   = (int*)(ws + OFF_CNT);
    int*    off   = (int*)(ws + OFF_OFF);
    int*    cur   = (int*)(ws + OFF_CUR);
    int*    eid   = (int*)(ws + OFF_EID);
    __bf16* Wb    = (__bf16*)(ws + OFF_WBF);
    float*  sum   = (float*)(ws + OFF_SUM);
    float*  sumsq = (float*)(ws + OFF_SUMSQ);
    float*  scale = (float*)(ws + OFF_SCALE);
    float*  shift = (float*)(ws + OFF_SHIFT);

    hipMemsetAsync(cnt, 0, N_TASK * sizeof(int), stream);
    hipMemsetAsync(ws + OFF_SUM, 0, 1024, stream);

    wcvt_kernel<<<(D_OUT * D_K + 255) / 256, 256, 0, stream>>>(W, Wb);
    hist_kernel<<<(N_EDGES + 255) / 256, 256, 0, stream>>>(row, col, cnt);
    scan_kernel<<<1, 1024, 0, stream>>>(cnt, off, cur);
    sid_kernel<<<(N_EDGES + 255) / 256, 256, 0, stream>>>(row, col, cur, eid);
    gather_kernel<<<(N_TASK + 3) / 4, 256, 0, stream>>>(edge_attr, off, eid, agg);
    gemm_kernel<<<(N_NODES + 63) / 64, 256, 0, stream>>>(agg, node_attr, Wb, bias,
                                                         out, sum, sumsq);
    bn_finalize_kernel<<<1, 128, 0, stream>>>(sum, sumsq, gamma, beta, scale, shift);
    bn_apply_kernel<<<(N_NODES * D_OUT / 8 + 255) / 256, 256, 0, stream>>>(out, scale, shift);
}

// Round 3
// 450.822 us; speedup vs baseline: 2.2542x; 1.5396x over previous
//
#include <hip/hip_runtime.h>
#include <hip/hip_bf16.h>

#define N_NODES 50000
#define N_EDGES 500000
#define D_IN    128
#define D_K     384
#define D_OUT   128
#define BN_EPS  1e-5f
#define N_TASK  (2 * N_NODES)   // recv tasks then send tasks
#define NB_SCAN ((N_TASK + 1023) / 1024)   // 98

typedef __bf16 bf16x8 __attribute__((ext_vector_type(8)));
typedef float  f32x4  __attribute__((ext_vector_type(4)));

// ---- workspace layout (bytes) ----
#define OFF_AGG   0ULL           // bf16 [2][50000][128] = 25,600,000
#define OFF_CNT   25600000ULL    // int  [100000]
#define OFF_OFF   26000000ULL    // int  [100001] (+pad)
#define OFF_CUR   26400256ULL    // int  [100000]
#define OFF_EID   26800256ULL    // int  [1000000]
#define OFF_WBF   30800256ULL    // bf16 [128][384]
#define OFF_SUM   30898560ULL
#define OFF_SUMSQ 30899072ULL
#define OFF_SCALE 30899584ULL
#define OFF_SHIFT 30900096ULL
#define OFF_BSUM  30900608ULL    // int [98]
#define OFF_BOFF  30901120ULL    // int [99]

// ---------------- W f32 -> bf16 ----------------
__global__ void wcvt_kernel(const float* __restrict__ W, __bf16* __restrict__ Wb) {
    int i = blockIdx.x * blockDim.x + threadIdx.x;
    if (i < D_OUT * D_K) Wb[i] = (__bf16)W[i];
}

// ---------------- degree histogram ----------------
__global__ __launch_bounds__(256) void hist_kernel(const int* __restrict__ row,
                                                   const int* __restrict__ col,
                                                   int* __restrict__ cnt) {
    int i = blockIdx.x * blockDim.x + threadIdx.x;
    if (i < N_EDGES) {
        atomicAdd(&cnt[col[i]], 1);
        atomicAdd(&cnt[N_NODES + row[i]], 1);
    }
}

// ---------------- scan phase A: per-block sums ----------------
__global__ __launch_bounds__(1024) void partial_kernel(const int* __restrict__ cnt,
                                                       int* __restrict__ bsum) {
    __shared__ int s[1024];
    const int idx = blockIdx.x * 1024 + threadIdx.x;
    s[threadIdx.x] = (idx < N_TASK) ? cnt[idx] : 0;
    __syncthreads();
    for (int ofs = 512; ofs > 0; ofs >>= 1) {
        if (threadIdx.x < ofs) s[threadIdx.x] += s[threadIdx.x + ofs];
        __syncthreads();
    }
    if (threadIdx.x == 0) bsum[blockIdx.x] = s[0];
}

// ---------------- scan phase B: scan of 98 block sums ----------------
__global__ void bscan_kernel(const int* __restrict__ bsum, int* __restrict__ boff) {
    if (threadIdx.x == 0) {
        int run = 0;
        for (int i = 0; i < NB_SCAN; ++i) { boff[i] = run; run += bsum[i]; }
        boff[NB_SCAN] = run;
    }
}

// ---------------- scan phase C: per-block scan + offset ----------------
__global__ __launch_bounds__(1024) void scanfin_kernel(const int* __restrict__ cnt,
                                                       const int* __restrict__ boff,
                                                       int* __restrict__ off,
                                                       int* __restrict__ cur) {
    __shared__ int s[1024];
    const int idx = blockIdx.x * 1024 + threadIdx.x;
    const int v = (idx < N_TASK) ? cnt[idx] : 0;
    s[threadIdx.x] = v;
    __syncthreads();
    for (int ofs = 1; ofs < 1024; ofs <<= 1) {
        int t = (threadIdx.x >= ofs) ? s[threadIdx.x - ofs] : 0;
        __syncthreads();
        s[threadIdx.x] += t;
        __syncthreads();
    }
    const int excl = boff[blockIdx.x] + s[threadIdx.x] - v;
    if (idx < N_TASK) { off[idx] = excl; cur[idx] = excl; }
    if (idx == N_TASK - 1) off[N_TASK] = excl + v;
}

// ---------------- scatter edge ids into CSR ----------------
__global__ __launch_bounds__(256) void sid_kernel(const int* __restrict__ row,
                                                  const int* __restrict__ col,
                                                  int* __restrict__ cur,
                                                  int* __restrict__ eid) {
    int i = blockIdx.x * blockDim.x + threadIdx.x;
    if (i < N_EDGES) {
        int p = atomicAdd(&cur[col[i]], 1);
        eid[p] = i;
        int q = atomicAdd(&cur[N_NODES + row[i]], 1);
        eid[q] = i;
    }
}

// ---------------- gather-sum: one wave per (node, side) task ----------------
__global__ __launch_bounds__(256) void gather_kernel(const float* __restrict__ edge_attr,
                                                     const int* __restrict__ off,
                                                     const int* __restrict__ eid,
                                                     __bf16* __restrict__ agg) {
    const int lane = threadIdx.x & 63;
    const int wid  = blockIdx.x * 4 + (threadIdx.x >> 6);
    if (wid >= N_TASK) return;
    const int beg = off[wid];
    const int end = off[wid + 1];
    float2 acc = {0.0f, 0.0f};
    for (int i = beg; i < end; ++i) {
        const int e = eid[i];
        const float2 v = ((const float2*)(edge_attr + (size_t)e * D_IN))[lane];
        acc.x += v.x;
        acc.y += v.y;
    }
    __bf16* p = agg + (size_t)wid * D_IN + 2 * lane;
    p[0] = (__bf16)acc.x;
    p[1] = (__bf16)acc.y;
}

// ---------------- fused GEMM (bf16 MFMA) + bias + ReLU + BN-stats ----------------
__global__ __launch_bounds__(256) void gemm_kernel(
    const __bf16* __restrict__ agg, const float* __restrict__ node_attr,
    const __bf16* __restrict__ Wb, const float* __restrict__ bias,
    float* __restrict__ h, float* __restrict__ sum, float* __restrict__ sumsq) {
    const int lane = threadIdx.x & 63;
    const int w    = threadIdx.x >> 6;
    const int m    = lane & 15;   // A-row (node) / C-col (channel) lane index
    const int g    = lane >> 4;   // k-group
    const int nodeA  = blockIdx.x * 64 + w * 16 + m;
    const bool validA = nodeA < N_NODES;

    f32x4 acc[8];
#pragma unroll
    for (int f = 0; f < 8; ++f) acc[f] = (f32x4)0.0f;

#pragma unroll
    for (int ks = 0; ks < 12; ++ks) {
        const int k0 = ks * 32;
        bf16x8 a;
#pragma unroll
        for (int i = 0; i < 8; ++i) a[i] = (__bf16)0.0f;
        if (validA) {
            if (ks < 8) {   // recv/send stored bf16
                const __bf16* p = agg + (size_t)(k0 >> 7) * (N_NODES * D_IN)
                                      + (size_t)nodeA * D_IN + (k0 & 127) + g * 8;
                a = *(const bf16x8*)p;
            } else {        // node_attr f32 -> bf16
                const float* p = node_attr + (size_t)nodeA * D_IN + (k0 - 256) + g * 8;
                f32x4 v0 = *(const f32x4*)p;
                f32x4 v1 = *(const f32x4*)(p + 4);
#pragma unroll
                for (int i = 0; i < 4; ++i) { a[i] = (__bf16)v0[i]; a[i + 4] = (__bf16)v1[i]; }
            }
        }
#pragma unroll
        for (int f = 0; f < 8; ++f) {
            const __bf16* wp = Wb + (size_t)(f * 16 + m) * D_K + k0 + g * 8;
            bf16x8 bfrag = *(const bf16x8*)wp;
            acc[f] = __builtin_amdgcn_mfma_f32_16x16x32_bf16(a, bfrag, acc[f], 0, 0, 0);
        }
    }

    // epilogue: bias + relu + write h + per-channel stats
#pragma unroll
    for (int f = 0; f < 8; ++f) {
        const int j  = f * 16 + m;
        const float bj = bias[j];
        float s1 = 0.0f, s2 = 0.0f;
#pragma unroll
        for (int r = 0; r < 4; ++r) {
            const int nodeC = blockIdx.x * 64 + w * 16 + g * 4 + r;
            float v = acc[f][r] + bj;
            v = v > 0.0f ? v : 0.0f;
            if (nodeC < N_NODES) {
                h[(size_t)nodeC * D_OUT + j] = v;
                s1 += v;
                s2 += v * v;
            }
        }
        s1 += __shfl_xor(s1, 16, 64);  s2 += __shfl_xor(s2, 16, 64);
        s1 += __shfl_xor(s1, 32, 64);  s2 += __shfl_xor(s2, 32, 64);
        if (lane < 16) {
            unsafeAtomicAdd(&sum[j], s1);
            unsafeAtomicAdd(&sumsq[j], s2);
        }
    }
}

// ---------------- BN finalize ----------------
__global__ void bn_finalize_kernel(const float* __restrict__ sum, const float* __restrict__ sumsq,
                                   const float* __restrict__ gamma, const float* __restrict__ beta,
                                   float* __restrict__ scale, float* __restrict__ shift) {
    int j = threadIdx.x;
    if (j < D_OUT) {
        const float inv_n = 1.0f / (float)N_NODES;
        float mu  = sum[j] * inv_n;
        float var = sumsq[j] * inv_n - mu * mu;
        float sc  = gamma[j] * rsqrtf(var + BN_EPS);
        scale[j] = sc;
        shift[j] = beta[j] - mu * sc;
    }
}

// ---------------- BN apply (in-place on d_out) ----------------
__global__ __launch_bounds__(256) void bn_apply_kernel(
    float* __restrict__ h, const float* __restrict__ scale, const float* __restrict__ shift) {
    size_t i = ((size_t)blockIdx.x * blockDim.x + threadIdx.x) * 8;
    if (i >= (size_t)N_NODES * D_OUT) return;
    const int j0 = (int)(i & 127);
    f32x4 a = *(const f32x4*)(h + i);
    f32x4 b = *(const f32x4*)(h + i + 4);
#pragma unroll
    for (int q = 0; q < 4; ++q) {
        a[q] = a[q] * scale[j0 + q]     + shift[j0 + q];
        b[q] = b[q] * scale[j0 + 4 + q] + shift[j0 + 4 + q];
    }
    *(f32x4*)(h + i)     = a;
    *(f32x4*)(h + i + 4) = b;
}

extern "C" void kernel_launch(void* const* d_in, const int* in_sizes, int n_in,
                              void* d_out, int out_size, void* d_ws, size_t ws_size,
                              hipStream_t stream) {
    const float* edge_attr = (const float*)d_in[0];
    const float* node_attr = (const float*)d_in[1];
    const float* W         = (const float*)d_in[2];
    const float* bias      = (const float*)d_in[3];
    const float* gamma     = (const float*)d_in[4];
    const float* beta      = (const float*)d_in[5];
    const int*   row       = (const int*)d_in[6];
    const int*   col       = (const int*)d_in[7];
    float* out = (float*)d_out;

    char* ws = (char*)d_ws;
    __bf16* agg   = (__bf16*)(ws + OFF_AGG);
    int*    cnt   = (int*)(ws + OFF_CNT);
    int*    off   = (int*)(ws + OFF_OFF);
    int*    cur   = (int*)(ws + OFF_CUR);
    int*    eid   = (int*)(ws + OFF_EID);
    __bf16* Wb    = (__bf16*)(ws + OFF_WBF);
    float*  sum   = (float*)(ws + OFF_SUM);
    float*  sumsq = (float*)(ws + OFF_SUMSQ);
    float*  scale = (float*)(ws + OFF_SCALE);
    float*  shift = (float*)(ws + OFF_SHIFT);
    int*    bsum  = (int*)(ws + OFF_BSUM);
    int*    boff  = (int*)(ws + OFF_BOFF);

    hipMemsetAsync(cnt, 0, N_TASK * sizeof(int), stream);
    hipMemsetAsync(ws + OFF_SUM, 0, 1024, stream);

    wcvt_kernel<<<(D_OUT * D_K + 255) / 256, 256, 0, stream>>>(W, Wb);
    hist_kernel<<<(N_EDGES + 255) / 256, 256, 0, stream>>>(row, col, cnt);
    partial_kernel<<<NB_SCAN, 1024, 0, stream>>>(cnt, bsum);
    bscan_kernel<<<1, 64, 0, stream>>>(bsum, boff);
    scanfin_kernel<<<NB_SCAN, 1024, 0, stream>>>(cnt, boff, off, cur);
    sid_kernel<<<(N_EDGES + 255) / 256, 256, 0, stream>>>(row, col, cur, eid);
    gather_kernel<<<(N_TASK + 3) / 4, 256, 0, stream>>>(edge_attr, off, eid, agg);
    gemm_kernel<<<(N_NODES + 63) / 64, 256, 0, stream>>>(agg, node_attr, Wb, bias,
                                                         out, sum, sumsq);
    bn_finalize_kernel<<<1, 128, 0, stream>>>(sum, sumsq, gamma, beta, scale, shift);
    bn_apply_kernel<<<(N_NODES * D_OUT / 8 + 255) / 256, 256, 0, stream>>>(out, scale, shift);
}

// Round 4
// 383.179 us; speedup vs baseline: 2.6521x; 1.1765x over previous
//
#include <hip/hip_runtime.h>
#include <hip/hip_bf16.h>

#define N_NODES 50000
#define N_EDGES 500000
#define D_IN    128
#define D_K     384
#define D_OUT   128
#define BN_EPS  1e-5f
#define N_TASK  (2 * N_NODES)   // recv tasks then send tasks
#define NB_SCAN ((N_TASK + 1023) / 1024)   // 98

typedef __bf16 bf16x8 __attribute__((ext_vector_type(8)));
typedef __bf16 bf16x4 __attribute__((ext_vector_type(4)));
typedef float  f32x4  __attribute__((ext_vector_type(4)));

// ---- workspace layout (bytes) ----
#define OFF_AGG   0ULL           // bf16 [2][50000][128] = 25,600,000
#define OFF_CNT   25600000ULL    // int  [100000]
#define OFF_OFF   26000000ULL    // int  [100001] (+pad)
#define OFF_CUR   26400256ULL    // int  [100000]
#define OFF_EID   26800256ULL    // int  [1000000]
#define OFF_WBF   30800256ULL    // bf16 [128][384]
#define OFF_SUM   30898560ULL
#define OFF_SUMSQ 30899072ULL
#define OFF_SCALE 30899584ULL
#define OFF_SHIFT 30900096ULL
#define OFF_BSUM  30900608ULL    // int [98]
#define OFF_BOFF  30901120ULL    // int [99]

// ---------------- W f32 -> bf16 ----------------
__global__ void wcvt_kernel(const float* __restrict__ W, __bf16* __restrict__ Wb) {
    int i = blockIdx.x * blockDim.x + threadIdx.x;
    if (i < D_OUT * D_K) Wb[i] = (__bf16)W[i];
}

// ---------------- degree histogram ----------------
__global__ __launch_bounds__(256) void hist_kernel(const int* __restrict__ row,
                                                   const int* __restrict__ col,
                                                   int* __restrict__ cnt) {
    int i = blockIdx.x * blockDim.x + threadIdx.x;
    if (i < N_EDGES) {
        atomicAdd(&cnt[col[i]], 1);
        atomicAdd(&cnt[N_NODES + row[i]], 1);
    }
}

// ---------------- scan phase A: per-block sums ----------------
__global__ __launch_bounds__(1024) void partial_kernel(const int* __restrict__ cnt,
                                                       int* __restrict__ bsum) {
    __shared__ int s[1024];
    const int idx = blockIdx.x * 1024 + threadIdx.x;
    s[threadIdx.x] = (idx < N_TASK) ? cnt[idx] : 0;
    __syncthreads();
    for (int ofs = 512; ofs > 0; ofs >>= 1) {
        if (threadIdx.x < ofs) s[threadIdx.x] += s[threadIdx.x + ofs];
        __syncthreads();
    }
    if (threadIdx.x == 0) bsum[blockIdx.x] = s[0];
}

// ---------------- scan phase B: scan of 98 block sums ----------------
__global__ void bscan_kernel(const int* __restrict__ bsum, int* __restrict__ boff) {
    if (threadIdx.x == 0) {
        int run = 0;
        for (int i = 0; i < NB_SCAN; ++i) { boff[i] = run; run += bsum[i]; }
        boff[NB_SCAN] = run;
    }
}

// ---------------- scan phase C: per-block scan + offset ----------------
__global__ __launch_bounds__(1024) void scanfin_kernel(const int* __restrict__ cnt,
                                                       const int* __restrict__ boff,
                                                       int* __restrict__ off,
                                                       int* __restrict__ cur) {
    __shared__ int s[1024];
    const int idx = blockIdx.x * 1024 + threadIdx.x;
    const int v = (idx < N_TASK) ? cnt[idx] : 0;
    s[threadIdx.x] = v;
    __syncthreads();
    for (int ofs = 1; ofs < 1024; ofs <<= 1) {
        int t = (threadIdx.x >= ofs) ? s[threadIdx.x - ofs] : 0;
        __syncthreads();
        s[threadIdx.x] += t;
        __syncthreads();
    }
    const int excl = boff[blockIdx.x] + s[threadIdx.x] - v;
    if (idx < N_TASK) { off[idx] = excl; cur[idx] = excl; }
    if (idx == N_TASK - 1) off[N_TASK] = excl + v;
}

// ---------------- scatter edge ids into CSR ----------------
__global__ __launch_bounds__(256) void sid_kernel(const int* __restrict__ row,
                                                  const int* __restrict__ col,
                                                  int* __restrict__ cur,
                                                  int* __restrict__ eid) {
    int i = blockIdx.x * blockDim.x + threadIdx.x;
    if (i < N_EDGES) {
        int p = atomicAdd(&cur[col[i]], 1);
        eid[p] = i;
        int q = atomicAdd(&cur[N_NODES + row[i]], 1);
        eid[q] = i;
    }
}

// ---------------- gather-sum: one wave per (node, side) task ----------------
// 2 edges per wave-iteration: lanes 0-31 -> edge j (float4 = 4 channels each),
// lanes 32-63 -> edge j+1. Edge IDs pre-loaded coalesced and shfl-broadcast.
__global__ __launch_bounds__(256) void gather_kernel(const float* __restrict__ edge_attr,
                                                     const int* __restrict__ off,
                                                     const int* __restrict__ eid,
                                                     __bf16* __restrict__ agg) {
    const int lane = threadIdx.x & 63;
    const int wid  = blockIdx.x * 4 + (threadIdx.x >> 6);
    if (wid >= N_TASK) return;
    const int beg = off[wid];
    const int end = off[wid + 1];
    const int hh  = lane >> 5;          // which edge of the pair
    const int c   = (lane & 31) * 4;    // channel base
    f32x4 acc = (f32x4)0.0f;

    for (int cbeg = beg; cbeg < end; cbeg += 64) {
        const int n = min(64, end - cbeg);
        const int e_reg = (lane < n) ? eid[cbeg + lane] : -1;
        int j = 0;
        for (; j + 8 <= n; j += 8) {
            const int e0 = __shfl(e_reg, j + 0 + hh);
            const int e1 = __shfl(e_reg, j + 2 + hh);
            const int e2 = __shfl(e_reg, j + 4 + hh);
            const int e3 = __shfl(e_reg, j + 6 + hh);
            const f32x4 v0 = *(const f32x4*)(edge_attr + (size_t)e0 * D_IN + c);
            const f32x4 v1 = *(const f32x4*)(edge_attr + (size_t)e1 * D_IN + c);
            const f32x4 v2 = *(const f32x4*)(edge_attr + (size_t)e2 * D_IN + c);
            const f32x4 v3 = *(const f32x4*)(edge_attr + (size_t)e3 * D_IN + c);
            acc += (v0 + v1) + (v2 + v3);
        }
        for (; j < n; j += 2) {
            const int e = __shfl(e_reg, j + hh);
            if (j + hh < n) {
                acc += *(const f32x4*)(edge_attr + (size_t)e * D_IN + c);
            }
        }
    }

    // combine the even-edge half (lanes 0-31) with the odd-edge half (lanes 32-63)
#pragma unroll
    for (int q = 0; q < 4; ++q) acc[q] += __shfl_xor(acc[q], 32);

    if (lane < 32) {
        bf16x4 o;
#pragma unroll
        for (int q = 0; q < 4; ++q) o[q] = (__bf16)acc[q];
        *(bf16x4*)(agg + (size_t)wid * D_IN + c) = o;
    }
}

// ---------------- fused GEMM (bf16 MFMA) + bias + ReLU + BN-stats ----------------
__global__ __launch_bounds__(256) void gemm_kernel(
    const __bf16* __restrict__ agg, const float* __restrict__ node_attr,
    const __bf16* __restrict__ Wb, const float* __restrict__ bias,
    float* __restrict__ h, float* __restrict__ sum, float* __restrict__ sumsq) {
    const int lane = threadIdx.x & 63;
    const int w    = threadIdx.x >> 6;
    const int m    = lane & 15;   // A-row (node) / C-col (channel) lane index
    const int g    = lane >> 4;   // k-group
    const int nodeA  = blockIdx.x * 64 + w * 16 + m;
    const bool validA = nodeA < N_NODES;

    f32x4 acc[8];
#pragma unroll
    for (int f = 0; f < 8; ++f) acc[f] = (f32x4)0.0f;

#pragma unroll
    for (int ks = 0; ks < 12; ++ks) {
        const int k0 = ks * 32;
        bf16x8 a;
#pragma unroll
        for (int i = 0; i < 8; ++i) a[i] = (__bf16)0.0f;
        if (validA) {
            if (ks < 8) {   // recv/send stored bf16
                const __bf16* p = agg + (size_t)(k0 >> 7) * (N_NODES * D_IN)
                                      + (size_t)nodeA * D_IN + (k0 & 127) + g * 8;
                a = *(const bf16x8*)p;
            } else {        // node_attr f32 -> bf16
                const float* p = node_attr + (size_t)nodeA * D_IN + (k0 - 256) + g * 8;
                f32x4 v0 = *(const f32x4*)p;
                f32x4 v1 = *(const f32x4*)(p + 4);
#pragma unroll
                for (int i = 0; i < 4; ++i) { a[i] = (__bf16)v0[i]; a[i + 4] = (__bf16)v1[i]; }
            }
        }
#pragma unroll
        for (int f = 0; f < 8; ++f) {
            const __bf16* wp = Wb + (size_t)(f * 16 + m) * D_K + k0 + g * 8;
            bf16x8 bfrag = *(const bf16x8*)wp;
            acc[f] = __builtin_amdgcn_mfma_f32_16x16x32_bf16(a, bfrag, acc[f], 0, 0, 0);
        }
    }

    // epilogue: bias + relu + write h + per-channel stats
#pragma unroll
    for (int f = 0; f < 8; ++f) {
        const int j  = f * 16 + m;
        const float bj = bias[j];
        float s1 = 0.0f, s2 = 0.0f;
#pragma unroll
        for (int r = 0; r < 4; ++r) {
            const int nodeC = blockIdx.x * 64 + w * 16 + g * 4 + r;
            float v = acc[f][r] + bj;
            v = v > 0.0f ? v : 0.0f;
            if (nodeC < N_NODES) {
                h[(size_t)nodeC * D_OUT + j] = v;
                s1 += v;
                s2 += v * v;
            }
        }
        s1 += __shfl_xor(s1, 16, 64);  s2 += __shfl_xor(s2, 16, 64);
        s1 += __shfl_xor(s1, 32, 64);  s2 += __shfl_xor(s2, 32, 64);
        if (lane < 16) {
            unsafeAtomicAdd(&sum[j], s1);
            unsafeAtomicAdd(&sumsq[j], s2);
        }
    }
}

// ---------------- BN finalize ----------------
__global__ void bn_finalize_kernel(const float* __restrict__ sum, const float* __restrict__ sumsq,
                                   const float* __restrict__ gamma, const float* __restrict__ beta,
                                   float* __restrict__ scale, float* __restrict__ shift) {
    int j = threadIdx.x;
    if (j < D_OUT) {
        const float inv_n = 1.0f / (float)N_NODES;
        float mu  = sum[j] * inv_n;
        float var = sumsq[j] * inv_n - mu * mu;
        float sc  = gamma[j] * rsqrtf(var + BN_EPS);
        scale[j] = sc;
        shift[j] = beta[j] - mu * sc;
    }
}

// ---------------- BN apply (in-place on d_out) ----------------
__global__ __launch_bounds__(256) void bn_apply_kernel(
    float* __restrict__ h, const float* __restrict__ scale, const float* __restrict__ shift) {
    size_t i = ((size_t)blockIdx.x * blockDim.x + threadIdx.x) * 8;
    if (i >= (size_t)N_NODES * D_OUT) return;
    const int j0 = (int)(i & 127);
    f32x4 a = *(const f32x4*)(h + i);
    f32x4 b = *(const f32x4*)(h + i + 4);
#pragma unroll
    for (int q = 0; q < 4; ++q) {
        a[q] = a[q] * scale[j0 + q]     + shift[j0 + q];
        b[q] = b[q] * scale[j0 + 4 + q] + shift[j0 + 4 + q];
    }
    *(f32x4*)(h + i)     = a;
    *(f32x4*)(h + i + 4) = b;
}

extern "C" void kernel_launch(void* const* d_in, const int* in_sizes, int n_in,
                              void* d_out, int out_size, void* d_ws, size_t ws_size,
                              hipStream_t stream) {
    const float* edge_attr = (const float*)d_in[0];
    const float* node_attr = (const float*)d_in[1];
    const float* W         = (const float*)d_in[2];
    const float* bias      = (const float*)d_in[3];
    const float* gamma     = (const float*)d_in[4];
    const float* beta      = (const float*)d_in[5];
    const int*   row       = (const int*)d_in[6];
    const int*   col       = (const int*)d_in[7];
    float* out = (float*)d_out;

    char* ws = (char*)d_ws;
    __bf16* agg   = (__bf16*)(ws + OFF_AGG);
    int*    cnt   = (int*)(ws + OFF_CNT);
    int*    off   = (int*)(ws + OFF_OFF);
    int*    cur   = (int*)(ws + OFF_CUR);
    int*    eid   = (int*)(ws + OFF_EID);
    __bf16* Wb    = (__bf16*)(ws + OFF_WBF);
    float*  sum   = (float*)(ws + OFF_SUM);
    float*  sumsq = (float*)(ws + OFF_SUMSQ);
    float*  scale = (float*)(ws + OFF_SCALE);
    float*  shift = (float*)(ws + OFF_SHIFT);
    int*    bsum  = (int*)(ws + OFF_BSUM);
    int*    boff  = (int*)(ws + OFF_BOFF);

    hipMemsetAsync(cnt, 0, N_TASK * sizeof(int), stream);
    hipMemsetAsync(ws + OFF_SUM, 0, 1024, stream);

    wcvt_kernel<<<(D_OUT * D_K + 255) / 256, 256, 0, stream>>>(W, Wb);
    hist_kernel<<<(N_EDGES + 255) / 256, 256, 0, stream>>>(row, col, cnt);
    partial_kernel<<<NB_SCAN, 1024, 0, stream>>>(cnt, bsum);
    bscan_kernel<<<1, 64, 0, stream>>>(bsum, boff);
    scanfin_kernel<<<NB_SCAN, 1024, 0, stream>>>(cnt, boff, off, cur);
    sid_kernel<<<(N_EDGES + 255) / 256, 256, 0, stream>>>(row, col, cur, eid);
    gather_kernel<<<(N_TASK + 3) / 4, 256, 0, stream>>>(edge_attr, off, eid, agg);
    gemm_kernel<<<(N_NODES + 63) / 64, 256, 0, stream>>>(agg, node_attr, Wb, bias,
                                                         out, sum, sumsq);
    bn_finalize_kernel<<<1, 128, 0, stream>>>(sum, sumsq, gamma, beta, scale, shift);
    bn_apply_kernel<<<(N_NODES * D_OUT / 8 + 255) / 256, 256, 0, stream>>>(out, scale, shift);
}

// Round 5
// 297.064 us; speedup vs baseline: 3.4209x; 1.2899x over previous
//
#include <hip/hip_runtime.h>
#include <hip/hip_bf16.h>

#define N_NODES 50000
#define N_EDGES 500000
#define D_IN    128
#define D_K     384
#define D_OUT   128
#define BN_EPS  1e-5f
#define N_TASK  (2 * N_NODES)   // recv tasks then send tasks
#define NB_SCAN ((N_TASK + 1023) / 1024)   // 98

typedef __bf16 bf16x8 __attribute__((ext_vector_type(8)));
typedef __bf16 bf16x4 __attribute__((ext_vector_type(4)));
typedef float  f32x4  __attribute__((ext_vector_type(4)));

// ---- workspace layout (bytes) ----
#define OFF_AGG   0ULL           // bf16 [2][50000][128] = 25,600,000
#define OFF_CNT   25600000ULL    // int  [100000]
#define OFF_OFF   26000000ULL    // int  [100001] (+pad)
#define OFF_CUR   26400256ULL    // int  [100000]
#define OFF_EID   26800256ULL    // int  [1000000]
#define OFF_WBF   30800256ULL    // bf16 [128][384]
#define OFF_SUM   30898560ULL
#define OFF_SUMSQ 30899072ULL
#define OFF_SCALE 30899584ULL
#define OFF_SHIFT 30900096ULL
#define OFF_BSUM  30900608ULL    // int [98]
#define OFF_BOFF  30901120ULL    // int [99]

// ---------------- W f32 -> bf16 ----------------
__global__ void wcvt_kernel(const float* __restrict__ W, __bf16* __restrict__ Wb) {
    int i = blockIdx.x * blockDim.x + threadIdx.x;
    if (i < D_OUT * D_K) Wb[i] = (__bf16)W[i];
}

// ---------------- degree histogram ----------------
__global__ __launch_bounds__(256) void hist_kernel(const int* __restrict__ row,
                                                   const int* __restrict__ col,
                                                   int* __restrict__ cnt) {
    int i = blockIdx.x * blockDim.x + threadIdx.x;
    if (i < N_EDGES) {
        atomicAdd(&cnt[col[i]], 1);
        atomicAdd(&cnt[N_NODES + row[i]], 1);
    }
}

// ---------------- scan phase A: per-block sums ----------------
__global__ __launch_bounds__(1024) void partial_kernel(const int* __restrict__ cnt,
                                                       int* __restrict__ bsum) {
    __shared__ int s[1024];
    const int idx = blockIdx.x * 1024 + threadIdx.x;
    s[threadIdx.x] = (idx < N_TASK) ? cnt[idx] : 0;
    __syncthreads();
    for (int ofs = 512; ofs > 0; ofs >>= 1) {
        if (threadIdx.x < ofs) s[threadIdx.x] += s[threadIdx.x + ofs];
        __syncthreads();
    }
    if (threadIdx.x == 0) bsum[blockIdx.x] = s[0];
}

// ---------------- scan phase B: scan of 98 block sums ----------------
__global__ void bscan_kernel(const int* __restrict__ bsum, int* __restrict__ boff) {
    if (threadIdx.x == 0) {
        int run = 0;
        for (int i = 0; i < NB_SCAN; ++i) { boff[i] = run; run += bsum[i]; }
        boff[NB_SCAN] = run;
    }
}

// ---------------- scan phase C: per-block scan + offset ----------------
__global__ __launch_bounds__(1024) void scanfin_kernel(const int* __restrict__ cnt,
                                                       const int* __restrict__ boff,
                                                       int* __restrict__ off,
                                                       int* __restrict__ cur) {
    __shared__ int s[1024];
    const int idx = blockIdx.x * 1024 + threadIdx.x;
    const int v = (idx < N_TASK) ? cnt[idx] : 0;
    s[threadIdx.x] = v;
    __syncthreads();
    for (int ofs = 1; ofs < 1024; ofs <<= 1) {
        int t = (threadIdx.x >= ofs) ? s[threadIdx.x - ofs] : 0;
        __syncthreads();
        s[threadIdx.x] += t;
        __syncthreads();
    }
    const int excl = boff[blockIdx.x] + s[threadIdx.x] - v;
    if (idx < N_TASK) { off[idx] = excl; cur[idx] = excl; }
    if (idx == N_TASK - 1) off[N_TASK] = excl + v;
}

// ---------------- scatter edge ids into CSR ----------------
__global__ __launch_bounds__(256) void sid_kernel(const int* __restrict__ row,
                                                  const int* __restrict__ col,
                                                  int* __restrict__ cur,
                                                  int* __restrict__ eid) {
    int i = blockIdx.x * blockDim.x + threadIdx.x;
    if (i < N_EDGES) {
        int p = atomicAdd(&cur[col[i]], 1);
        eid[p] = i;
        int q = atomicAdd(&cur[N_NODES + row[i]], 1);
        eid[q] = i;
    }
}

// ---------------- gather-sum: one wave per (node, side) task ----------------
__global__ __launch_bounds__(256) void gather_kernel(const float* __restrict__ edge_attr,
                                                     const int* __restrict__ off,
                                                     const int* __restrict__ eid,
                                                     __bf16* __restrict__ agg) {
    const int lane = threadIdx.x & 63;
    const int wid  = blockIdx.x * 4 + (threadIdx.x >> 6);
    if (wid >= N_TASK) return;
    const int beg = off[wid];
    const int end = off[wid + 1];
    const int hh  = lane >> 5;          // which edge of the pair
    const int c   = (lane & 31) * 4;    // channel base
    f32x4 acc = (f32x4)0.0f;

    for (int cbeg = beg; cbeg < end; cbeg += 64) {
        const int n = min(64, end - cbeg);
        const int e_reg = (lane < n) ? eid[cbeg + lane] : -1;
        int j = 0;
        for (; j + 8 <= n; j += 8) {
            const int e0 = __shfl(e_reg, j + 0 + hh);
            const int e1 = __shfl(e_reg, j + 2 + hh);
            const int e2 = __shfl(e_reg, j + 4 + hh);
            const int e3 = __shfl(e_reg, j + 6 + hh);
            const f32x4 v0 = *(const f32x4*)(edge_attr + (size_t)e0 * D_IN + c);
            const f32x4 v1 = *(const f32x4*)(edge_attr + (size_t)e1 * D_IN + c);
            const f32x4 v2 = *(const f32x4*)(edge_attr + (size_t)e2 * D_IN + c);
            const f32x4 v3 = *(const f32x4*)(edge_attr + (size_t)e3 * D_IN + c);
            acc += (v0 + v1) + (v2 + v3);
        }
        for (; j < n; j += 2) {
            const int e = __shfl(e_reg, j + hh);
            if (j + hh < n) {
                acc += *(const f32x4*)(edge_attr + (size_t)e * D_IN + c);
            }
        }
    }

#pragma unroll
    for (int q = 0; q < 4; ++q) acc[q] += __shfl_xor(acc[q], 32);

    if (lane < 32) {
        bf16x4 o;
#pragma unroll
        for (int q = 0; q < 4; ++q) o[q] = (__bf16)acc[q];
        *(bf16x4*)(agg + (size_t)wid * D_IN + c) = o;
    }
}

// ---------------- fused GEMM + bias + ReLU + BN-stats ----------------
// grid (nodeTiles, 2): blockIdx.y = channel half (64 ch). W-half staged in LDS
// (XOR-swizzled, T2). Block = 4 waves; wave w -> nodes [bx*128 + w*32, +32).
#define ROW_B 768   // bytes per W row in LDS (384 * 2)
__global__ __launch_bounds__(256) void gemm_kernel(
    const __bf16* __restrict__ agg, const float* __restrict__ node_attr,
    const __bf16* __restrict__ Wb, const float* __restrict__ bias,
    float* __restrict__ h, float* __restrict__ sum, float* __restrict__ sumsq) {
    __shared__ __align__(16) char Ws[64 * ROW_B];   // 49152 B

    const int lane = threadIdx.x & 63;
    const int w    = threadIdx.x >> 6;
    const int m    = lane & 15;   // A-row / C-col lane index
    const int g    = lane >> 4;   // k-group
    const int cy   = blockIdx.y;  // channel half

    // ---- stage W-half into LDS, swizzled: byte ^= ((row&7)<<4) ----
    {
        const __bf16* src = Wb + (size_t)cy * 64 * D_K;
#pragma unroll
        for (int i = 0; i < 12; ++i) {
            const int idx = i * 256 + threadIdx.x;        // vec16 index, 3072 total
            const int r   = idx / 48;                     // 48 vec16 per row
            const int cb  = (idx % 48) * 16;              // byte offset in row
            bf16x8 v = *(const bf16x8*)(src + (size_t)r * D_K + (idx % 48) * 8);
            *(bf16x8*)(Ws + r * ROW_B + (cb ^ ((r & 7) << 4))) = v;
        }
    }
    __syncthreads();

    const int nodeA0 = blockIdx.x * 128 + w * 32 + m;
    const int nodeA1 = nodeA0 + 16;

    f32x4 acc[2][4];
#pragma unroll
    for (int i = 0; i < 2; ++i)
#pragma unroll
        for (int f = 0; f < 4; ++f) acc[i][f] = (f32x4)0.0f;

#pragma unroll
    for (int ks = 0; ks < 12; ++ks) {
        const int k0 = ks * 32;
        bf16x8 a0, a1;
#pragma unroll
        for (int i = 0; i < 8; ++i) { a0[i] = (__bf16)0.0f; a1[i] = (__bf16)0.0f; }
        if (ks < 8) {   // recv/send stored bf16
            const size_t base = (size_t)(k0 >> 7) * (N_NODES * D_IN) + (k0 & 127) + g * 8;
            if (nodeA0 < N_NODES) a0 = *(const bf16x8*)(agg + base + (size_t)nodeA0 * D_IN);
            if (nodeA1 < N_NODES) a1 = *(const bf16x8*)(agg + base + (size_t)nodeA1 * D_IN);
        } else {        // node_attr f32 -> bf16
            const size_t base = (k0 - 256) + g * 8;
            if (nodeA0 < N_NODES) {
                const float* p = node_attr + (size_t)nodeA0 * D_IN + base;
                f32x4 v0 = *(const f32x4*)p, v1 = *(const f32x4*)(p + 4);
#pragma unroll
                for (int i = 0; i < 4; ++i) { a0[i] = (__bf16)v0[i]; a0[i + 4] = (__bf16)v1[i]; }
            }
            if (nodeA1 < N_NODES) {
                const float* p = node_attr + (size_t)nodeA1 * D_IN + base;
                f32x4 v0 = *(const f32x4*)p, v1 = *(const f32x4*)(p + 4);
#pragma unroll
                for (int i = 0; i < 4; ++i) { a1[i] = (__bf16)v0[i]; a1[i + 4] = (__bf16)v1[i]; }
            }
        }
#pragma unroll
        for (int f = 0; f < 4; ++f) {
            const int r = f * 16 + m;
            const int cb = (k0 + g * 8) * 2;
            bf16x8 bfrag = *(const bf16x8*)(Ws + r * ROW_B + (cb ^ ((r & 7) << 4)));
            acc[0][f] = __builtin_amdgcn_mfma_f32_16x16x32_bf16(a0, bfrag, acc[0][f], 0, 0, 0);
            acc[1][f] = __builtin_amdgcn_mfma_f32_16x16x32_bf16(a1, bfrag, acc[1][f], 0, 0, 0);
        }
    }

    // epilogue: bias + relu + write h + per-channel stats
#pragma unroll
    for (int f = 0; f < 4; ++f) {
        const int j  = cy * 64 + f * 16 + m;
        const float bj = bias[j];
        float s1 = 0.0f, s2 = 0.0f;
#pragma unroll
        for (int i = 0; i < 2; ++i) {
#pragma unroll
            for (int r = 0; r < 4; ++r) {
                const int nodeC = blockIdx.x * 128 + w * 32 + i * 16 + g * 4 + r;
                float v = acc[i][f][r] + bj;
                v = v > 0.0f ? v : 0.0f;
                if (nodeC < N_NODES) {
                    h[(size_t)nodeC * D_OUT + j] = v;
                    s1 += v;
                    s2 += v * v;
                }
            }
        }
        s1 += __shfl_xor(s1, 16, 64);  s2 += __shfl_xor(s2, 16, 64);
        s1 += __shfl_xor(s1, 32, 64);  s2 += __shfl_xor(s2, 32, 64);
        if (lane < 16) {
            unsafeAtomicAdd(&sum[j], s1);
            unsafeAtomicAdd(&sumsq[j], s2);
        }
    }
}

// ---------------- BN finalize ----------------
__global__ void bn_finalize_kernel(const float* __restrict__ sum, const float* __restrict__ sumsq,
                                   const float* __restrict__ gamma, const float* __restrict__ beta,
                                   float* __restrict__ scale, float* __restrict__ shift) {
    int j = threadIdx.x;
    if (j < D_OUT) {
        const float inv_n = 1.0f / (float)N_NODES;
        float mu  = sum[j] * inv_n;
        float var = sumsq[j] * inv_n - mu * mu;
        float sc  = gamma[j] * rsqrtf(var + BN_EPS);
        scale[j] = sc;
        shift[j] = beta[j] - mu * sc;
    }
}

// ---------------- BN apply (in-place on d_out) ----------------
__global__ __launch_bounds__(256) void bn_apply_kernel(
    float* __restrict__ h, const float* __restrict__ scale, const float* __restrict__ shift) {
    size_t i = ((size_t)blockIdx.x * blockDim.x + threadIdx.x) * 8;
    if (i >= (size_t)N_NODES * D_OUT) return;
    const int j0 = (int)(i & 127);
    f32x4 a = *(const f32x4*)(h + i);
    f32x4 b = *(const f32x4*)(h + i + 4);
#pragma unroll
    for (int q = 0; q < 4; ++q) {
        a[q] = a[q] * scale[j0 + q]     + shift[j0 + q];
        b[q] = b[q] * scale[j0 + 4 + q] + shift[j0 + 4 + q];
    }
    *(f32x4*)(h + i)     = a;
    *(f32x4*)(h + i + 4) = b;
}

extern "C" void kernel_launch(void* const* d_in, const int* in_sizes, int n_in,
                              void* d_out, int out_size, void* d_ws, size_t ws_size,
                              hipStream_t stream) {
    const float* edge_attr = (const float*)d_in[0];
    const float* node_attr = (const float*)d_in[1];
    const float* W         = (const float*)d_in[2];
    const float* bias      = (const float*)d_in[3];
    const float* gamma     = (const float*)d_in[4];
    const float* beta      = (const float*)d_in[5];
    const int*   row       = (const int*)d_in[6];
    const int*   col       = (const int*)d_in[7];
    float* out = (float*)d_out;

    char* ws = (char*)d_ws;
    __bf16* agg   = (__bf16*)(ws + OFF_AGG);
    int*    cnt   = (int*)(ws + OFF_CNT);
    int*    off   = (int*)(ws + OFF_OFF);
    int*    cur   = (int*)(ws + OFF_CUR);
    int*    eid   = (int*)(ws + OFF_EID);
    __bf16* Wb    = (__bf16*)(ws + OFF_WBF);
    float*  sum   = (float*)(ws + OFF_SUM);
    float*  sumsq = (float*)(ws + OFF_SUMSQ);
    float*  scale = (float*)(ws + OFF_SCALE);
    float*  shift = (float*)(ws + OFF_SHIFT);
    int*    bsum  = (int*)(ws + OFF_BSUM);
    int*    boff  = (int*)(ws + OFF_BOFF);

    hipMemsetAsync(cnt, 0, N_TASK * sizeof(int), stream);
    hipMemsetAsync(ws + OFF_SUM, 0, 1024, stream);

    wcvt_kernel<<<(D_OUT * D_K + 255) / 256, 256, 0, stream>>>(W, Wb);
    hist_kernel<<<(N_EDGES + 255) / 256, 256, 0, stream>>>(row, col, cnt);
    partial_kernel<<<NB_SCAN, 1024, 0, stream>>>(cnt, bsum);
    bscan_kernel<<<1, 64, 0, stream>>>(bsum, boff);
    scanfin_kernel<<<NB_SCAN, 1024, 0, stream>>>(cnt, boff, off, cur);
    sid_kernel<<<(N_EDGES + 255) / 256, 256, 0, stream>>>(row, col, cur, eid);
    gather_kernel<<<(N_TASK + 3) / 4, 256, 0, stream>>>(edge_attr, off, eid, agg);
    dim3 ggrid((N_NODES + 127) / 128, 2);
    gemm_kernel<<<ggrid, 256, 0, stream>>>(agg, node_attr, Wb, bias, out, sum, sumsq);
    bn_finalize_kernel<<<1, 128, 0, stream>>>(sum, sumsq, gamma, beta, scale, shift);
    bn_apply_kernel<<<(N_NODES * D_OUT / 8 + 255) / 256, 256, 0, stream>>>(out, scale, shift);
}

// Round 6
// 212.203 us; speedup vs baseline: 4.7889x; 1.3999x over previous
//
#include <hip/hip_runtime.h>
#include <hip/hip_bf16.h>

#define N_NODES 50000
#define N_EDGES 500000
#define D_IN    128
#define D_K     384
#define D_OUT   128
#define BN_EPS  1e-5f
#define N_TASK  (2 * N_NODES)   // recv tasks then send tasks
#define NB_SCAN ((N_TASK + 1023) / 1024)   // 98
#define NBX     ((N_NODES + 127) / 128)    // 391 gemm x-blocks
#define PSTRIDE 400                        // padded partial stride (>= NBX)

typedef __bf16 bf16x8 __attribute__((ext_vector_type(8)));
typedef __bf16 bf16x4 __attribute__((ext_vector_type(4)));
typedef float  f32x4  __attribute__((ext_vector_type(4)));

// ---- workspace layout (bytes) ----
#define OFF_AGG   0ULL           // bf16 [2][50000][128] = 25,600,000
#define OFF_CNT   25600000ULL    // int  [100000]
#define OFF_OFF   26000000ULL    // int  [100001] (+pad)
#define OFF_EID   26400256ULL    // int  [1000000]       = 4,000,000
#define OFF_RKC   30400256ULL    // int  [500000]        = 2,000,000
#define OFF_RKR   32400256ULL    // int  [500000]        = 2,000,000
#define OFF_WBF   34400256ULL    // bf16 [128][384]      =    98,304
#define OFF_PSTAT 34498560ULL    // f32  [256][400]      =   409,600
#define OFF_SCALE 34908160ULL
#define OFF_SHIFT 34908672ULL
#define OFF_BSUM  34909184ULL    // int [98]
#define OFF_BOFF  34909696ULL    // int [99]

// ---------------- W f32 -> bf16 ----------------
__global__ void wcvt_kernel(const float* __restrict__ W, __bf16* __restrict__ Wb) {
    int i = blockIdx.x * blockDim.x + threadIdx.x;
    if (i < D_OUT * D_K) Wb[i] = (__bf16)W[i];
}

// ---------------- degree histogram + per-edge ranks ----------------
__global__ __launch_bounds__(256) void hist_kernel(const int* __restrict__ row,
                                                   const int* __restrict__ col,
                                                   int* __restrict__ cnt,
                                                   int* __restrict__ rank_c,
                                                   int* __restrict__ rank_r) {
    int i = blockIdx.x * blockDim.x + threadIdx.x;
    if (i < N_EDGES) {
        rank_c[i] = atomicAdd(&cnt[col[i]], 1);
        rank_r[i] = atomicAdd(&cnt[N_NODES + row[i]], 1);
    }
}

// ---------------- scan phase A: per-block sums ----------------
__global__ __launch_bounds__(1024) void partial_kernel(const int* __restrict__ cnt,
                                                       int* __restrict__ bsum) {
    __shared__ int s[1024];
    const int idx = blockIdx.x * 1024 + threadIdx.x;
    s[threadIdx.x] = (idx < N_TASK) ? cnt[idx] : 0;
    __syncthreads();
    for (int ofs = 512; ofs > 0; ofs >>= 1) {
        if (threadIdx.x < ofs) s[threadIdx.x] += s[threadIdx.x + ofs];
        __syncthreads();
    }
    if (threadIdx.x == 0) bsum[blockIdx.x] = s[0];
}

// ---------------- scan phase B: scan of 98 block sums ----------------
__global__ void bscan_kernel(const int* __restrict__ bsum, int* __restrict__ boff) {
    if (threadIdx.x == 0) {
        int run = 0;
        for (int i = 0; i < NB_SCAN; ++i) { boff[i] = run; run += bsum[i]; }
        boff[NB_SCAN] = run;
    }
}

// ---------------- scan phase C: per-block scan + offset ----------------
__global__ __launch_bounds__(1024) void scanfin_kernel(const int* __restrict__ cnt,
                                                       const int* __restrict__ boff,
                                                       int* __restrict__ off) {
    __shared__ int s[1024];
    const int idx = blockIdx.x * 1024 + threadIdx.x;
    const int v = (idx < N_TASK) ? cnt[idx] : 0;
    s[threadIdx.x] = v;
    __syncthreads();
    for (int ofs = 1; ofs < 1024; ofs <<= 1) {
        int t = (threadIdx.x >= ofs) ? s[threadIdx.x - ofs] : 0;
        __syncthreads();
        s[threadIdx.x] += t;
        __syncthreads();
    }
    const int excl = boff[blockIdx.x] + s[threadIdx.x] - v;
    if (idx < N_TASK) off[idx] = excl;
    if (idx == N_TASK - 1) off[N_TASK] = excl + v;
}

// ---------------- place edge ids into CSR (no atomics: rank-based) ----------------
__global__ __launch_bounds__(256) void sid_kernel(const int* __restrict__ row,
                                                  const int* __restrict__ col,
                                                  const int* __restrict__ off,
                                                  const int* __restrict__ rank_c,
                                                  const int* __restrict__ rank_r,
                                                  int* __restrict__ eid) {
    int i = blockIdx.x * blockDim.x + threadIdx.x;
    if (i < N_EDGES) {
        eid[off[col[i]] + rank_c[i]] = i;
        eid[off[N_NODES + row[i]] + rank_r[i]] = i;
    }
}

// ---------------- gather-sum: one wave per (node, side) task ----------------
// 16-edge chunks; 8 independent predicated 16B loads per pass (lanes 0-31 take
// even edges, lanes 32-63 odd edges of the chunk; each half-wave covers a full
// 512B edge row). Typical degree ~10 -> single pass, 8 loads in flight.
__global__ __launch_bounds__(256) void gather_kernel(const float* __restrict__ edge_attr,
                                                     const int* __restrict__ off,
                                                     const int* __restrict__ eid,
                                                     __bf16* __restrict__ agg) {
    const int lane = threadIdx.x & 63;
    const int wid  = blockIdx.x * 4 + (threadIdx.x >> 6);
    if (wid >= N_TASK) return;
    const int beg = off[wid];
    const int end = off[wid + 1];
    const int hh  = lane >> 5;          // which edge of each pair
    const int c   = (lane & 31) * 4;    // channel base
    f32x4 acc0 = (f32x4)0.0f, acc1 = (f32x4)0.0f;

    for (int cbeg = beg; cbeg < end; cbeg += 16) {
        const int n = min(16, end - cbeg);
        const int e_reg = (lane < n) ? eid[cbeg + lane] : 0;
#pragma unroll
        for (int k = 0; k < 8; ++k) {
            const int jj = 2 * k + hh;
            const int e  = __shfl(e_reg, jj);
            if (jj < n) {
                const f32x4 v = *(const f32x4*)(edge_attr + (size_t)e * D_IN + c);
                if (k & 1) acc1 += v; else acc0 += v;
            }
        }
    }
    acc0 += acc1;

    // combine even-edge half (lanes 0-31) with odd-edge half (lanes 32-63)
#pragma unroll
    for (int q = 0; q < 4; ++q) acc0[q] += __shfl_xor(acc0[q], 32);

    if (lane < 32) {
        bf16x4 o;
#pragma unroll
        for (int q = 0; q < 4; ++q) o[q] = (__bf16)acc0[q];
        *(bf16x4*)(agg + (size_t)wid * D_IN + c) = o;
    }
}

// ---------------- fused GEMM + bias + ReLU + BN-partials ----------------
// grid (NBX, 2): blockIdx.y = channel half (64 ch). W-half staged in LDS
// (XOR-swizzled). Block = 4 waves; wave w -> nodes [bx*128 + w*32, +32).
// Per-channel stats exit as per-block partials (NO atomics).
#define ROW_B 768   // bytes per W row in LDS (384 * 2)
__global__ __launch_bounds__(256) void gemm_kernel(
    const __bf16* __restrict__ agg, const float* __restrict__ node_attr,
    const __bf16* __restrict__ Wb, const float* __restrict__ bias,
    float* __restrict__ h, float* __restrict__ pstat) {
    __shared__ __align__(16) char Ws[64 * ROW_B];   // 49152 B
    __shared__ float sred[2][4][64];                // +2048 B

    const int lane = threadIdx.x & 63;
    const int w    = threadIdx.x >> 6;
    const int m    = lane & 15;   // A-row / C-col lane index
    const int g    = lane >> 4;   // k-group
    const int cy   = blockIdx.y;  // channel half

    // ---- stage W-half into LDS, swizzled: byte ^= ((row&7)<<4) ----
    {
        const __bf16* src = Wb + (size_t)cy * 64 * D_K;
#pragma unroll
        for (int i = 0; i < 12; ++i) {
            const int idx = i * 256 + threadIdx.x;        // vec16 index, 3072 total
            const int r   = idx / 48;                     // 48 vec16 per row
            const int cb  = (idx % 48) * 16;              // byte offset in row
            bf16x8 v = *(const bf16x8*)(src + (size_t)r * D_K + (idx % 48) * 8);
            *(bf16x8*)(Ws + r * ROW_B + (cb ^ ((r & 7) << 4))) = v;
        }
    }
    __syncthreads();

    const int nodeA0 = blockIdx.x * 128 + w * 32 + m;
    const int nodeA1 = nodeA0 + 16;

    f32x4 acc[2][4];
#pragma unroll
    for (int i = 0; i < 2; ++i)
#pragma unroll
        for (int f = 0; f < 4; ++f) acc[i][f] = (f32x4)0.0f;

#pragma unroll
    for (int ks = 0; ks < 12; ++ks) {
        const int k0 = ks * 32;
        bf16x8 a0, a1;
#pragma unroll
        for (int i = 0; i < 8; ++i) { a0[i] = (__bf16)0.0f; a1[i] = (__bf16)0.0f; }
        if (ks < 8) {   // recv/send stored bf16
            const size_t base = (size_t)(k0 >> 7) * (N_NODES * D_IN) + (k0 & 127) + g * 8;
            if (nodeA0 < N_NODES) a0 = *(const bf16x8*)(agg + base + (size_t)nodeA0 * D_IN);
            if (nodeA1 < N_NODES) a1 = *(const bf16x8*)(agg + base + (size_t)nodeA1 * D_IN);
        } else {        // node_attr f32 -> bf16
            const size_t base = (k0 - 256) + g * 8;
            if (nodeA0 < N_NODES) {
                const float* p = node_attr + (size_t)nodeA0 * D_IN + base;
                f32x4 v0 = *(const f32x4*)p, v1 = *(const f32x4*)(p + 4);
#pragma unroll
                for (int i = 0; i < 4; ++i) { a0[i] = (__bf16)v0[i]; a0[i + 4] = (__bf16)v1[i]; }
            }
            if (nodeA1 < N_NODES) {
                const float* p = node_attr + (size_t)nodeA1 * D_IN + base;
                f32x4 v0 = *(const f32x4*)p, v1 = *(const f32x4*)(p + 4);
#pragma unroll
                for (int i = 0; i < 4; ++i) { a1[i] = (__bf16)v0[i]; a1[i + 4] = (__bf16)v1[i]; }
            }
        }
#pragma unroll
        for (int f = 0; f < 4; ++f) {
            const int r = f * 16 + m;
            const int cb = (k0 + g * 8) * 2;
            bf16x8 bfrag = *(const bf16x8*)(Ws + r * ROW_B + (cb ^ ((r & 7) << 4)));
            acc[0][f] = __builtin_amdgcn_mfma_f32_16x16x32_bf16(a0, bfrag, acc[0][f], 0, 0, 0);
            acc[1][f] = __builtin_amdgcn_mfma_f32_16x16x32_bf16(a1, bfrag, acc[1][f], 0, 0, 0);
        }
    }

    // epilogue: bias + relu + write h + per-wave channel stats into LDS
#pragma unroll
    for (int f = 0; f < 4; ++f) {
        const int j  = cy * 64 + f * 16 + m;
        const float bj = bias[j];
        float s1 = 0.0f, s2 = 0.0f;
#pragma unroll
        for (int i = 0; i < 2; ++i) {
#pragma unroll
            for (int r = 0; r < 4; ++r) {
                const int nodeC = blockIdx.x * 128 + w * 32 + i * 16 + g * 4 + r;
                float v = acc[i][f][r] + bj;
                v = v > 0.0f ? v : 0.0f;
                if (nodeC < N_NODES) {
                    h[(size_t)nodeC * D_OUT + j] = v;
                    s1 += v;
                    s2 += v * v;
                }
            }
        }
        s1 += __shfl_xor(s1, 16, 64);  s2 += __shfl_xor(s2, 16, 64);
        s1 += __shfl_xor(s1, 32, 64);  s2 += __shfl_xor(s2, 32, 64);
        if (lane < 16) { sred[0][w][f * 16 + m] = s1; sred[1][w][f * 16 + m] = s2; }
    }
    __syncthreads();
    if (threadIdx.x < 128) {
        const int s = threadIdx.x >> 6;
        const int c = threadIdx.x & 63;
        const float v = sred[s][0][c] + sred[s][1][c] + sred[s][2][c] + sred[s][3][c];
        pstat[(size_t)(s * 128 + cy * 64 + c) * PSTRIDE + blockIdx.x] = v;
    }
}

// ---------------- BN finalize: reduce partials + scale/shift ----------------
__global__ __launch_bounds__(256) void bn_finalize_kernel(
    const float* __restrict__ pstat, const float* __restrict__ gamma,
    const float* __restrict__ beta, float* __restrict__ scale, float* __restrict__ shift) {
    const int j = blockIdx.x;   // channel 0..127
    float a1 = 0.0f, a2 = 0.0f;
    for (int b = threadIdx.x; b < NBX; b += 256) {
        a1 += pstat[(size_t)j * PSTRIDE + b];
        a2 += pstat[(size_t)(128 + j) * PSTRIDE + b];
    }
#pragma unroll
    for (int ofs = 32; ofs >= 1; ofs >>= 1) {
        a1 += __shfl_xor(a1, ofs, 64);
        a2 += __shfl_xor(a2, ofs, 64);
    }
    __shared__ float w1[4], w2[4];
    if ((threadIdx.x & 63) == 0) { w1[threadIdx.x >> 6] = a1; w2[threadIdx.x >> 6] = a2; }
    __syncthreads();
    if (threadIdx.x == 0) {
        const float S1 = w1[0] + w1[1] + w1[2] + w1[3];
        const float S2 = w2[0] + w2[1] + w2[2] + w2[3];
        const float inv_n = 1.0f / (float)N_NODES;
        const float mu  = S1 * inv_n;
        const float var = S2 * inv_n - mu * mu;
        const float sc  = gamma[j] * rsqrtf(var + BN_EPS);
        scale[j] = sc;
        shift[j] = beta[j] - mu * sc;
    }
}

// ---------------- BN apply (in-place on d_out) ----------------
__global__ __launch_bounds__(256) void bn_apply_kernel(
    float* __restrict__ h, const float* __restrict__ scale, const float* __restrict__ shift) {
    size_t i = ((size_t)blockIdx.x * blockDim.x + threadIdx.x) * 8;
    if (i >= (size_t)N_NODES * D_OUT) return;
    const int j0 = (int)(i & 127);
    f32x4 a = *(const f32x4*)(h + i);
    f32x4 b = *(const f32x4*)(h + i + 4);
#pragma unroll
    for (int q = 0; q < 4; ++q) {
        a[q] = a[q] * scale[j0 + q]     + shift[j0 + q];
        b[q] = b[q] * scale[j0 + 4 + q] + shift[j0 + 4 + q];
    }
    *(f32x4*)(h + i)     = a;
    *(f32x4*)(h + i + 4) = b;
}

extern "C" void kernel_launch(void* const* d_in, const int* in_sizes, int n_in,
                              void* d_out, int out_size, void* d_ws, size_t ws_size,
                              hipStream_t stream) {
    const float* edge_attr = (const float*)d_in[0];
    const float* node_attr = (const float*)d_in[1];
    const float* W         = (const float*)d_in[2];
    const float* bias      = (const float*)d_in[3];
    const float* gamma     = (const float*)d_in[4];
    const float* beta      = (const float*)d_in[5];
    const int*   row       = (const int*)d_in[6];
    const int*   col       = (const int*)d_in[7];
    float* out = (float*)d_out;

    char* ws = (char*)d_ws;
    __bf16* agg    = (__bf16*)(ws + OFF_AGG);
    int*    cnt    = (int*)(ws + OFF_CNT);
    int*    off    = (int*)(ws + OFF_OFF);
    int*    eid    = (int*)(ws + OFF_EID);
    int*    rank_c = (int*)(ws + OFF_RKC);
    int*    rank_r = (int*)(ws + OFF_RKR);
    __bf16* Wb     = (__bf16*)(ws + OFF_WBF);
    float*  pstat  = (float*)(ws + OFF_PSTAT);
    float*  scale  = (float*)(ws + OFF_SCALE);
    float*  shift  = (float*)(ws + OFF_SHIFT);
    int*    bsum   = (int*)(ws + OFF_BSUM);
    int*    boff   = (int*)(ws + OFF_BOFF);

    hipMemsetAsync(cnt, 0, N_TASK * sizeof(int), stream);

    wcvt_kernel<<<(D_OUT * D_K + 255) / 256, 256, 0, stream>>>(W, Wb);
    hist_kernel<<<(N_EDGES + 255) / 256, 256, 0, stream>>>(row, col, cnt, rank_c, rank_r);
    partial_kernel<<<NB_SCAN, 1024, 0, stream>>>(cnt, bsum);
    bscan_kernel<<<1, 64, 0, stream>>>(bsum, boff);
    scanfin_kernel<<<NB_SCAN, 1024, 0, stream>>>(cnt, boff, off);
    sid_kernel<<<(N_EDGES + 255) / 256, 256, 0, stream>>>(row, col, off, rank_c, rank_r, eid);
    gather_kernel<<<(N_TASK + 3) / 4, 256, 0, stream>>>(edge_attr, off, eid, agg);
    dim3 ggrid(NBX, 2);
    gemm_kernel<<<ggrid, 256, 0, stream>>>(agg, node_attr, Wb, bias, out, pstat);
    bn_finalize_kernel<<<128, 256, 0, stream>>>(pstat, gamma, beta, scale, shift);
    bn_apply_kernel<<<(N_NODES * D_OUT / 8 + 255) / 256, 256, 0, stream>>>(out, scale, shift);
}

// Round 7
// 201.681 us; speedup vs baseline: 5.0388x; 1.0522x over previous
//
#include <hip/hip_runtime.h>
#include <hip/hip_bf16.h>

#define N_NODES 50000
#define N_EDGES 500000
#define D_IN    128
#define D_K     384
#define D_OUT   128
#define BN_EPS  1e-5f
#define N_TASK  (2 * N_NODES)   // recv tasks then send tasks
#define NB_SCAN ((N_TASK + 1023) / 1024)   // 98
#define NBX     ((N_NODES + 255) / 256)    // 196 gemm x-blocks (256 nodes each)
#define PSTRIDE 200                        // padded partial stride (>= NBX)

typedef __bf16 bf16x8 __attribute__((ext_vector_type(8)));
typedef __bf16 bf16x4 __attribute__((ext_vector_type(4)));
typedef float  f32x4  __attribute__((ext_vector_type(4)));

// ---- workspace layout (bytes) ----
#define OFF_AGG   0ULL           // bf16 [2][50000][128] = 25,600,000
#define OFF_CNT   25600000ULL    // int  [100000]
#define OFF_OFF   26000000ULL    // int  [100001] (+pad)
#define OFF_EID   26400256ULL    // int  [1000000]       = 4,000,000
#define OFF_RKC   30400256ULL    // int  [500000]        = 2,000,000
#define OFF_RKR   32400256ULL    // int  [500000]        = 2,000,000
#define OFF_PSTAT 34400256ULL    // f32  [256][200]      =   204,800
#define OFF_SCALE 34605056ULL
#define OFF_SHIFT 34605568ULL
#define OFF_BSUM  34606080ULL    // int [98]

// ---------------- degree histogram + per-edge ranks ----------------
__global__ __launch_bounds__(256) void hist_kernel(const int* __restrict__ row,
                                                   const int* __restrict__ col,
                                                   int* __restrict__ cnt,
                                                   int* __restrict__ rank_c,
                                                   int* __restrict__ rank_r) {
    int i = blockIdx.x * blockDim.x + threadIdx.x;
    if (i < N_EDGES) {
        rank_c[i] = atomicAdd(&cnt[col[i]], 1);
        rank_r[i] = atomicAdd(&cnt[N_NODES + row[i]], 1);
    }
}

// ---------------- scan phase A: per-block sums ----------------
__global__ __launch_bounds__(1024) void partial_kernel(const int* __restrict__ cnt,
                                                       int* __restrict__ bsum) {
    __shared__ int s[1024];
    const int idx = blockIdx.x * 1024 + threadIdx.x;
    s[threadIdx.x] = (idx < N_TASK) ? cnt[idx] : 0;
    __syncthreads();
    for (int ofs = 512; ofs > 0; ofs >>= 1) {
        if (threadIdx.x < ofs) s[threadIdx.x] += s[threadIdx.x + ofs];
        __syncthreads();
    }
    if (threadIdx.x == 0) bsum[blockIdx.x] = s[0];
}

// ---------------- scan phase B: per-block scan (block offset re-derived in-block) --------
__global__ __launch_bounds__(1024) void scanfin_kernel(const int* __restrict__ cnt,
                                                       const int* __restrict__ bsum,
                                                       int* __restrict__ off) {
    __shared__ int sb[128];
    __shared__ int s[1024];
    // inclusive scan of the 98 block sums (all threads hit the barriers)
    if (threadIdx.x < 128) sb[threadIdx.x] = (threadIdx.x < NB_SCAN) ? bsum[threadIdx.x] : 0;
    __syncthreads();
    for (int ofs = 1; ofs < 128; ofs <<= 1) {
        int t = 0;
        if (threadIdx.x < 128 && threadIdx.x >= ofs) t = sb[threadIdx.x - ofs];
        __syncthreads();
        if (threadIdx.x < 128) sb[threadIdx.x] += t;
        __syncthreads();
    }
    const int boff = (blockIdx.x == 0) ? 0 : sb[blockIdx.x - 1];

    const int idx = blockIdx.x * 1024 + threadIdx.x;
    const int v = (idx < N_TASK) ? cnt[idx] : 0;
    s[threadIdx.x] = v;
    __syncthreads();
    for (int ofs = 1; ofs < 1024; ofs <<= 1) {
        int t = (threadIdx.x >= ofs) ? s[threadIdx.x - ofs] : 0;
        __syncthreads();
        s[threadIdx.x] += t;
        __syncthreads();
    }
    const int excl = boff + s[threadIdx.x] - v;
    if (idx < N_TASK) off[idx] = excl;
    if (idx == N_TASK - 1) off[N_TASK] = excl + v;
}

// ---------------- place edge ids into CSR (no atomics: rank-based) ----------------
__global__ __launch_bounds__(256) void sid_kernel(const int* __restrict__ row,
                                                  const int* __restrict__ col,
                                                  const int* __restrict__ off,
                                                  const int* __restrict__ rank_c,
                                                  const int* __restrict__ rank_r,
                                                  int* __restrict__ eid) {
    int i = blockIdx.x * blockDim.x + threadIdx.x;
    if (i < N_EDGES) {
        eid[off[col[i]] + rank_c[i]] = i;
        eid[off[N_NODES + row[i]] + rank_r[i]] = i;
    }
}

// ---------------- gather-sum: one wave per (node, side) task ----------------
__global__ __launch_bounds__(256) void gather_kernel(const float* __restrict__ edge_attr,
                                                     const int* __restrict__ off,
                                                     const int* __restrict__ eid,
                                                     __bf16* __restrict__ agg) {
    const int lane = threadIdx.x & 63;
    const int wid  = blockIdx.x * 4 + (threadIdx.x >> 6);
    if (wid >= N_TASK) return;
    const int beg = off[wid];
    const int end = off[wid + 1];
    const int hh  = lane >> 5;          // which edge of each pair
    const int c   = (lane & 31) * 4;    // channel base
    f32x4 acc0 = (f32x4)0.0f, acc1 = (f32x4)0.0f;

    for (int cbeg = beg; cbeg < end; cbeg += 16) {
        const int n = min(16, end - cbeg);
        const int e_reg = (lane < n) ? eid[cbeg + lane] : 0;
#pragma unroll
        for (int k = 0; k < 8; ++k) {
            const int jj = 2 * k + hh;
            const int e  = __shfl(e_reg, jj);
            if (jj < n) {
                const f32x4 v = *(const f32x4*)(edge_attr + (size_t)e * D_IN + c);
                if (k & 1) acc1 += v; else acc0 += v;
            }
        }
    }
    acc0 += acc1;

#pragma unroll
    for (int q = 0; q < 4; ++q) acc0[q] += __shfl_xor(acc0[q], 32);

    if (lane < 32) {
        bf16x4 o;
#pragma unroll
        for (int q = 0; q < 4; ++q) o[q] = (__bf16)acc0[q];
        *(bf16x4*)(agg + (size_t)wid * D_IN + c) = o;
    }
}

// ---------------- fused GEMM + bias + ReLU + BN-partials ----------------
// grid (NBX, 2): blockIdx.y = channel half (64 ch). W-half staged f32->bf16 into
// LDS (XOR-swizzled). Block = 8 waves (512 thr); wave w -> nodes
// [bx*256 + w*32, +32). Per-channel stats exit as per-block partials.
#define ROW_B 768   // bytes per W row in LDS (384 * 2)
__global__ __launch_bounds__(512) void gemm_kernel(
    const __bf16* __restrict__ agg, const float* __restrict__ node_attr,
    const float* __restrict__ W, const float* __restrict__ bias,
    float* __restrict__ h, float* __restrict__ pstat) {
    __shared__ __align__(16) char Ws[64 * ROW_B];   // 49152 B
    __shared__ float sred[2][8][64];                // +4096 B

    const int lane = threadIdx.x & 63;
    const int w    = threadIdx.x >> 6;
    const int m    = lane & 15;   // A-row / C-col lane index
    const int g    = lane >> 4;   // k-group
    const int cy   = blockIdx.y;  // channel half

    // ---- stage W-half into LDS (f32 -> bf16), swizzled: byte ^= ((row&7)<<4) ----
    {
        const float* src = W + (size_t)cy * 64 * D_K;
#pragma unroll
        for (int i = 0; i < 6; ++i) {
            const int idx = i * 512 + threadIdx.x;        // vec16 index, 3072 total
            const int r   = idx / 48;                     // 48 vec16 per row
            const int c8  = idx % 48;                     // 8-elem group in row
            const float* p = src + (size_t)r * D_K + c8 * 8;
            f32x4 v0 = *(const f32x4*)p, v1 = *(const f32x4*)(p + 4);
            bf16x8 v;
#pragma unroll
            for (int q = 0; q < 4; ++q) { v[q] = (__bf16)v0[q]; v[q + 4] = (__bf16)v1[q]; }
            *(bf16x8*)(Ws + r * ROW_B + ((c8 * 16) ^ ((r & 7) << 4))) = v;
        }
    }
    __syncthreads();

    const int nodeA0 = blockIdx.x * 256 + w * 32 + m;
    const int nodeA1 = nodeA0 + 16;

    f32x4 acc[2][4];
#pragma unroll
    for (int i = 0; i < 2; ++i)
#pragma unroll
        for (int f = 0; f < 4; ++f) acc[i][f] = (f32x4)0.0f;

#pragma unroll
    for (int ks = 0; ks < 12; ++ks) {
        const int k0 = ks * 32;
        bf16x8 a0, a1;
#pragma unroll
        for (int i = 0; i < 8; ++i) { a0[i] = (__bf16)0.0f; a1[i] = (__bf16)0.0f; }
        if (ks < 8) {   // recv/send stored bf16
            const size_t base = (size_t)(k0 >> 7) * (N_NODES * D_IN) + (k0 & 127) + g * 8;
            if (nodeA0 < N_NODES) a0 = *(const bf16x8*)(agg + base + (size_t)nodeA0 * D_IN);
            if (nodeA1 < N_NODES) a1 = *(const bf16x8*)(agg + base + (size_t)nodeA1 * D_IN);
        } else {        // node_attr f32 -> bf16
            const size_t base = (k0 - 256) + g * 8;
            if (nodeA0 < N_NODES) {
                const float* p = node_attr + (size_t)nodeA0 * D_IN + base;
                f32x4 v0 = *(const f32x4*)p, v1 = *(const f32x4*)(p + 4);
#pragma unroll
                for (int i = 0; i < 4; ++i) { a0[i] = (__bf16)v0[i]; a0[i + 4] = (__bf16)v1[i]; }
            }
            if (nodeA1 < N_NODES) {
                const float* p = node_attr + (size_t)nodeA1 * D_IN + base;
                f32x4 v0 = *(const f32x4*)p, v1 = *(const f32x4*)(p + 4);
#pragma unroll
                for (int i = 0; i < 4; ++i) { a1[i] = (__bf16)v0[i]; a1[i + 4] = (__bf16)v1[i]; }
            }
        }
#pragma unroll
        for (int f = 0; f < 4; ++f) {
            const int r = f * 16 + m;
            const int cb = (k0 + g * 8) * 2;
            bf16x8 bfrag = *(const bf16x8*)(Ws + r * ROW_B + (cb ^ ((r & 7) << 4)));
            acc[0][f] = __builtin_amdgcn_mfma_f32_16x16x32_bf16(a0, bfrag, acc[0][f], 0, 0, 0);
            acc[1][f] = __builtin_amdgcn_mfma_f32_16x16x32_bf16(a1, bfrag, acc[1][f], 0, 0, 0);
        }
    }

    // epilogue: bias + relu + write h + per-wave channel stats into LDS
#pragma unroll
    for (int f = 0; f < 4; ++f) {
        const int j  = cy * 64 + f * 16 + m;
        const float bj = bias[j];
        float s1 = 0.0f, s2 = 0.0f;
#pragma unroll
        for (int i = 0; i < 2; ++i) {
#pragma unroll
            for (int r = 0; r < 4; ++r) {
                const int nodeC = blockIdx.x * 256 + w * 32 + i * 16 + g * 4 + r;
                float v = acc[i][f][r] + bj;
                v = v > 0.0f ? v : 0.0f;
                if (nodeC < N_NODES) {
                    h[(size_t)nodeC * D_OUT + j] = v;
                    s1 += v;
                    s2 += v * v;
                }
            }
        }
        s1 += __shfl_xor(s1, 16, 64);  s2 += __shfl_xor(s2, 16, 64);
        s1 += __shfl_xor(s1, 32, 64);  s2 += __shfl_xor(s2, 32, 64);
        if (lane < 16) { sred[0][w][f * 16 + m] = s1; sred[1][w][f * 16 + m] = s2; }
    }
    __syncthreads();
    if (threadIdx.x < 128) {
        const int s = threadIdx.x >> 6;
        const int c = threadIdx.x & 63;
        float v = 0.0f;
#pragma unroll
        for (int q = 0; q < 8; ++q) v += sred[s][q][c];
        pstat[(size_t)(s * 128 + cy * 64 + c) * PSTRIDE + blockIdx.x] = v;
    }
}

// ---------------- BN finalize: reduce partials + scale/shift ----------------
__global__ __launch_bounds__(256) void bn_finalize_kernel(
    const float* __restrict__ pstat, const float* __restrict__ gamma,
    const float* __restrict__ beta, float* __restrict__ scale, float* __restrict__ shift) {
    const int j = blockIdx.x;   // channel 0..127
    float a1 = 0.0f, a2 = 0.0f;
    for (int b = threadIdx.x; b < NBX; b += 256) {
        a1 += pstat[(size_t)j * PSTRIDE + b];
        a2 += pstat[(size_t)(128 + j) * PSTRIDE + b];
    }
#pragma unroll
    for (int ofs = 32; ofs >= 1; ofs >>= 1) {
        a1 += __shfl_xor(a1, ofs, 64);
        a2 += __shfl_xor(a2, ofs, 64);
    }
    __shared__ float w1[4], w2[4];
    if ((threadIdx.x & 63) == 0) { w1[threadIdx.x >> 6] = a1; w2[threadIdx.x >> 6] = a2; }
    __syncthreads();
    if (threadIdx.x == 0) {
        const float S1 = w1[0] + w1[1] + w1[2] + w1[3];
        const float S2 = w2[0] + w2[1] + w2[2] + w2[3];
        const float inv_n = 1.0f / (float)N_NODES;
        const float mu  = S1 * inv_n;
        const float var = S2 * inv_n - mu * mu;
        const float sc  = gamma[j] * rsqrtf(var + BN_EPS);
        scale[j] = sc;
        shift[j] = beta[j] - mu * sc;
    }
}

// ---------------- BN apply (in-place on d_out) ----------------
__global__ __launch_bounds__(256) void bn_apply_kernel(
    float* __restrict__ h, const float* __restrict__ scale, const float* __restrict__ shift) {
    size_t i = ((size_t)blockIdx.x * blockDim.x + threadIdx.x) * 8;
    if (i >= (size_t)N_NODES * D_OUT) return;
    const int j0 = (int)(i & 127);
    f32x4 a = *(const f32x4*)(h + i);
    f32x4 b = *(const f32x4*)(h + i + 4);
#pragma unroll
    for (int q = 0; q < 4; ++q) {
        a[q] = a[q] * scale[j0 + q]     + shift[j0 + q];
        b[q] = b[q] * scale[j0 + 4 + q] + shift[j0 + 4 + q];
    }
    *(f32x4*)(h + i)     = a;
    *(f32x4*)(h + i + 4) = b;
}

extern "C" void kernel_launch(void* const* d_in, const int* in_sizes, int n_in,
                              void* d_out, int out_size, void* d_ws, size_t ws_size,
                              hipStream_t stream) {
    const float* edge_attr = (const float*)d_in[0];
    const float* node_attr = (const float*)d_in[1];
    const float* W         = (const float*)d_in[2];
    const float* bias      = (const float*)d_in[3];
    const float* gamma     = (const float*)d_in[4];
    const float* beta      = (const float*)d_in[5];
    const int*   row       = (const int*)d_in[6];
    const int*   col       = (const int*)d_in[7];
    float* out = (float*)d_out;

    char* ws = (char*)d_ws;
    __bf16* agg    = (__bf16*)(ws + OFF_AGG);
    int*    cnt    = (int*)(ws + OFF_CNT);
    int*    off    = (int*)(ws + OFF_OFF);
    int*    eid    = (int*)(ws + OFF_EID);
    int*    rank_c = (int*)(ws + OFF_RKC);
    int*    rank_r = (int*)(ws + OFF_RKR);
    float*  pstat  = (float*)(ws + OFF_PSTAT);
    float*  scale  = (float*)(ws + OFF_SCALE);
    float*  shift  = (float*)(ws + OFF_SHIFT);
    int*    bsum   = (int*)(ws + OFF_BSUM);

    hipMemsetAsync(cnt, 0, N_TASK * sizeof(int), stream);

    hist_kernel<<<(N_EDGES + 255) / 256, 256, 0, stream>>>(row, col, cnt, rank_c, rank_r);
    partial_kernel<<<NB_SCAN, 1024, 0, stream>>>(cnt, bsum);
    scanfin_kernel<<<NB_SCAN, 1024, 0, stream>>>(cnt, bsum, off);
    sid_kernel<<<(N_EDGES + 255) / 256, 256, 0, stream>>>(row, col, off, rank_c, rank_r, eid);
    gather_kernel<<<(N_TASK + 3) / 4, 256, 0, stream>>>(edge_attr, off, eid, agg);
    dim3 ggrid(NBX, 2);
    gemm_kernel<<<ggrid, 512, 0, stream>>>(agg, node_attr, W, bias, out, pstat);
    bn_finalize_kernel<<<128, 256, 0, stream>>>(pstat, gamma, beta, scale, shift);
    bn_apply_kernel<<<(N_NODES * D_OUT / 8 + 255) / 256, 256, 0, stream>>>(out, scale, shift);
}